// Round 6
// baseline (105.622 us; speedup 1.0000x reference)
//
#include <hip/hip_runtime.h>
#include <hip/hip_bf16.h>

#define Bn 8192
#define Dn 256
#define MARGIN_F 0.5f

typedef short short8 __attribute__((ext_vector_type(8)));
typedef float floatx4 __attribute__((ext_vector_type(4)));

// RNE fp32 -> bf16
__device__ inline unsigned short f2bf(float f) {
    unsigned int u = __float_as_uint(f);
    unsigned int r = (u + 0x7fffu + ((u >> 16) & 1u)) >> 16;
    return (unsigned short)r;
}

// ws layout. embT is k-group-transposed: 16-B unit embT[(k>>3)*Bn + j] holds
// bf16 elements (k&~7)..(k|7) of row j. Fragment loads (quarter-wave = 16
// consecutive rows) are contiguous 256 B -> fully coalesced.
#define OFF_SQ   ((size_t)Bn * Dn * 2)
#define OFF_POS  (OFF_SQ + Bn * 4)
#define OFF_NEG  (OFF_POS + Bn * 4)
#define OFF_ACC  (OFF_NEG + Bn * 4)   // [0]=total f32, [1]=count f32, [2]=ticket u32

// ---------------- prep: bf16 cast + k-group transpose, sq[i], init ----------
__global__ __launch_bounds__(256) void prep_kernel(
        const float* __restrict__ emb, unsigned short* __restrict__ embT,
        float* __restrict__ sq, unsigned int* __restrict__ posb,
        unsigned int* __restrict__ negb, unsigned int* __restrict__ accs) {
    const int w = threadIdx.x >> 6;
    const int lane = threadIdx.x & 63;
    const int row = blockIdx.x * 4 + w;   // grid = Bn/4, one wave per row

    const float4 v = *(const float4*)(emb + (size_t)row * Dn + lane * 4);
    float ss = v.x * v.x + v.y * v.y + v.z * v.z + v.w * v.w;
    #pragma unroll
    for (int m = 32; m >= 1; m >>= 1) ss += __shfl_xor(ss, m);

    uint2 o;
    o.x = (unsigned int)f2bf(v.x) | ((unsigned int)f2bf(v.y) << 16);
    o.y = (unsigned int)f2bf(v.z) | ((unsigned int)f2bf(v.w) << 16);
    // lane holds k = 4*lane .. 4*lane+3 -> k-group lane>>1, half lane&1
    const int kg = lane >> 1;
    *(uint2*)(embT + ((size_t)kg * Bn + row) * 8 + (lane & 1) * 4) = o;

    if (lane == 0) {
        sq[row] = ss;
        posb[row] = 0u;            // sentinel: real encoded scores are > 0
        negb[row] = 0xFFFFFFFFu;   // sentinel: real encoded scores are smaller
    }
    if (blockIdx.x == 0 && threadIdx.x == 0) {
        accs[0] = 0u; accs[1] = 0u; accs[2] = 0u;
    }
}

// ---------------- mine v4: 64 i-rows/wave (4 m-tiles) + LDS-shared B --------
// R4 post-mortem: v3's pin landed aFrag in AGPRs (VGPR_Count=64 = exactly
// aFrag's size; no scratch traffic; dur v2==v3) -> A was NEVER restreamed and
// the "A restream" theory was wrong. Real cost split: LDS reads 1.07 GB
// (~20us), VALU ~20us, MFMA 13.8us, L2 ~9us, poorly overlapped. Both LDS and
// VALU scale with wave count -> double the per-wave i-tile to 64 rows so each
// B ds_read_b128 feeds 4 MFMAs: LDS volume halves (0.54 GB), per-wave
// overhead halves, MFMA invariant. Grid (32,16)=512 blocks=2/CU, both
// resident at __launch_bounds__(256,2) (~250 combined V+AGPR, budget 256).
__global__ __launch_bounds__(256, 2) void mine_kernel(
        const unsigned short* __restrict__ embT, const float* __restrict__ sq,
        const int* __restrict__ labels, unsigned int* __restrict__ posb,
        unsigned int* __restrict__ negb) {
    const int tid  = threadIdx.x;
    const int w    = tid >> 6;
    const int lane = tid & 63;
    const int quad = lane >> 4;
    const int c    = lane & 15;

    const int iBase = blockIdx.x * 256 + w * 64;   // block: 256 i, wave: 64 i
    const int jBase = blockIdx.y * 512;            // block j-window: 512

    const size_t KS = (size_t)4 * Bn * 8;   // shorts per k-step (4 k-groups)

    // LDS B tile: unit (kg, j) at index kg*32 + j, 16 B each. 2 x 16 KB.
    __shared__ __align__(16) unsigned short Bt[2][32 * 32 * 8];
    __shared__ float sqJ[512];
    __shared__ int   labJ[512];

    // A fragments: resident (AGPR-parked) for the whole j-loop. 4 m x 8 ks.
    short8 aFrag[4][8];
    #pragma unroll
    for (int m = 0; m < 4; ++m) {
        const unsigned short* ap = embT + ((size_t)quad * Bn + iBase + m * 16 + c) * 8;
        #pragma unroll
        for (int ks = 0; ks < 8; ++ks)
            aFrag[m][ks] = *(const short8*)(ap + ks * KS);
    }
    // Pin: an asm def can't be rematerialized -> fragments stay resident
    // (VGPR or AGPR; MFMA reads A from AGPR directly) instead of re-streamed.
    #pragma unroll
    for (int m = 0; m < 4; ++m)
        #pragma unroll
        for (int ks = 0; ks < 8; ++ks)
            asm volatile("" : "+v"(aFrag[m][ks]));

    // labels of the rows this lane reduces (C/D rows: quad*4+r)
    int labI[4][4];
    #pragma unroll
    for (int m = 0; m < 4; ++m)
        #pragma unroll
        for (int r = 0; r < 4; ++r)
            labI[m][r] = labels[iBase + m * 16 + quad * 4 + r];

    float rpos[4][4], rneg[4][4];
    #pragma unroll
    for (int m = 0; m < 4; ++m)
        #pragma unroll
        for (int r = 0; r < 4; ++r) { rpos[m][r] = -1e30f; rneg[m][r] = 1e30f; }

    // Stage j-window metadata once: 2 floats + 2 ints per thread.
    {
        const int t2 = tid * 2;
        *(float2*)&sqJ[t2] = *(const float2*)&sq[jBase + t2];
        *(int2*)&labJ[t2]  = *(const int2*)&labels[jBase + t2];
    }

    // Staging: thread t stages LDS units u = t + 256*cc (cc=0..3), which is
    // (kg = (t>>5) + 8*cc, jcol = t&31). LDS dest is wave-uniform base +
    // lane*16 (linear), global src is per-lane -> legal for global_load_lds.
    const unsigned short* sbase = embT + ((size_t)(tid >> 5) * Bn + jBase + (tid & 31)) * 8;

    #define STAGE(BUF, JT) do {                                                        \
        const unsigned short* _s = sbase + (size_t)(JT) * 32 * 8;                      \
        unsigned short* _d = &Bt[BUF][(size_t)tid * 8];                                \
        _Pragma("unroll")                                                              \
        for (int cc = 0; cc < 4; ++cc)                                                 \
            __builtin_amdgcn_global_load_lds(                                          \
                (const __attribute__((address_space(1))) unsigned int*)                \
                    (_s + (size_t)cc * 8 * Bn * 8),                                    \
                (__attribute__((address_space(3))) unsigned int*)(_d + cc * 256 * 8),  \
                16, 0, 0);                                                             \
    } while (0)

    STAGE(0, 0);
    __syncthreads();   // buf0 + sqJ/labJ ready (syncthreads drains vmcnt)

    for (int jt = 0; jt < 16; ++jt) {
        if (jt + 1 < 16) STAGE((jt + 1) & 1, jt + 1);   // prefetch overlaps compute
        const unsigned short* bt = Bt[jt & 1];
        #pragma unroll
        for (int n = 0; n < 2; ++n) {
            const int jc = jt * 32 + n * 16 + c;
            const float sj = sqJ[jc];          // broadcast ds_read (quads share)
            const int   lj = labJ[jc];
            floatx4 acc[4];
            #pragma unroll
            for (int m = 0; m < 4; ++m) acc[m] = (floatx4){0.f, 0.f, 0.f, 0.f};
            #pragma unroll
            for (int ks = 0; ks < 8; ++ks) {
                short8 bF = *(const short8*)(bt +
                    (size_t)((ks * 4 + quad) * 32 + n * 16 + c) * 8);
                #pragma unroll
                for (int m = 0; m < 4; ++m)
                    acc[m] = __builtin_amdgcn_mfma_f32_16x16x32_bf16(
                        aFrag[m][ks], bF, acc[m], 0, 0, 0);
            }
            // s = sq_j - 2*dot: monotone proxy for dist. Diagonal is the
            // row-minimum s -> harmless inside the positive-max.
            #pragma unroll
            for (int m = 0; m < 4; ++m)
                #pragma unroll
                for (int r = 0; r < 4; ++r) {
                    float s = fmaf(-2.0f, acc[m][r], sj);
                    bool  e = (lj == labI[m][r]);
                    rpos[m][r] = e ? fmaxf(rpos[m][r], s) : rpos[m][r];
                    rneg[m][r] = e ? rneg[m][r] : fminf(rneg[m][r], s);
                }
        }
        __syncthreads();   // stage(jt+1) landed; all waves done with buf jt&1
    }
    #undef STAGE

    // reduce over the 16 c-lanes of each quad; encode s+4 (>0) so uint order
    // == float order; merge via atomics.
    #pragma unroll
    for (int m = 0; m < 4; ++m)
        #pragma unroll
        for (int r = 0; r < 4; ++r) {
            float p = rpos[m][r], q = rneg[m][r];
            #pragma unroll
            for (int msk = 1; msk <= 8; msk <<= 1) {
                p = fmaxf(p, __shfl_xor(p, msk));
                q = fminf(q, __shfl_xor(q, msk));
            }
            if (c == 0) {
                int ig = iBase + m * 16 + quad * 4 + r;
                if (p > -1e29f) atomicMax(&posb[ig], __float_as_uint(p + 4.0f));
                if (q <  1e29f) atomicMin(&negb[ig], __float_as_uint(q + 4.0f));
            }
        }
}

// ---------------- finalize: partial sums + last-block divide -----------------
__global__ __launch_bounds__(256) void finalize_kernel(
        const float* __restrict__ sq, const unsigned int* __restrict__ posb,
        const unsigned int* __restrict__ negb, float* __restrict__ accsF,
        unsigned int* __restrict__ accsU, float* __restrict__ out) {
    const int i = blockIdx.x * 256 + threadIdx.x;
    unsigned int pb = posb[i], nb = negb[i];
    bool hp = (pb != 0u);
    bool hn = (nb != 0xFFFFFFFFu);
    float si  = sq[i];
    float dap = sqrtf(fmaxf(si + (__uint_as_float(pb) - 4.0f), 0.0f));
    float dan = sqrtf(fmaxf(si + (__uint_as_float(nb) - 4.0f), 0.0f));
    bool valid = hp && hn && (dan < dap + MARGIN_F);
    float t  = valid ? fmaxf(dap - dan + MARGIN_F, 0.0f) : 0.0f;
    float cc = valid ? 1.0f : 0.0f;
    #pragma unroll
    for (int m = 32; m >= 1; m >>= 1) {
        t  += __shfl_xor(t, m);
        cc += __shfl_xor(cc, m);
    }
    __shared__ float sT[4], sC[4];
    int w = threadIdx.x >> 6, lane = threadIdx.x & 63;
    if (lane == 0) { sT[w] = t; sC[w] = cc; }
    __syncthreads();
    if (threadIdx.x == 0) {
        atomicAdd(&accsF[0], sT[0] + sT[1] + sT[2] + sT[3]);
        atomicAdd(&accsF[1], sC[0] + sC[1] + sC[2] + sC[3]);
        __threadfence();
        unsigned int ticket = atomicAdd(&accsU[2], 1u);
        if (ticket == gridDim.x - 1) {
            float tot = atomicAdd(&accsF[0], 0.0f);
            float cnt = atomicAdd(&accsF[1], 0.0f);
            out[0] = (cnt > 0.0f) ? tot / cnt : 0.0f;
        }
    }
}

extern "C" void kernel_launch(void* const* d_in, const int* in_sizes, int n_in,
                              void* d_out, int out_size, void* d_ws, size_t ws_size,
                              hipStream_t stream) {
    const float* emb   = (const float*)d_in[0];
    const int*  labels = (const int*)d_in[1];
    float* out = (float*)d_out;

    char* ws = (char*)d_ws;
    unsigned short* embT = (unsigned short*)ws;
    float*        sqv  = (float*)(ws + OFF_SQ);
    unsigned int* posb = (unsigned int*)(ws + OFF_POS);
    unsigned int* negb = (unsigned int*)(ws + OFF_NEG);
    float*        accsF = (float*)(ws + OFF_ACC);
    unsigned int* accsU = (unsigned int*)(ws + OFF_ACC);

    prep_kernel<<<Bn / 4, 256, 0, stream>>>(emb, embT, sqv, posb, negb, accsU);
    mine_kernel<<<dim3(32, 16), 256, 0, stream>>>(embT, sqv, labels, posb, negb);
    finalize_kernel<<<Bn / 256, 256, 0, stream>>>(sqv, posb, negb, accsF, accsU, out);
}

// Round 12
// 103.793 us; speedup vs baseline: 1.0176x; 1.0176x over previous
//
#include <hip/hip_runtime.h>
#include <hip/hip_bf16.h>

#define Bn 8192
#define Dn 256
#define MARGIN_F 0.5f

typedef short short8 __attribute__((ext_vector_type(8)));
typedef float floatx4 __attribute__((ext_vector_type(4)));

// RNE fp32 -> bf16
__device__ inline unsigned short f2bf(float f) {
    unsigned int u = __float_as_uint(f);
    unsigned int r = (u + 0x7fffu + ((u >> 16) & 1u)) >> 16;
    return (unsigned short)r;
}

// ws layout. embT is k-group-transposed: 16-B unit embT[(k>>3)*Bn + j] holds
// bf16 elements (k&~7)..(k|7) of row j. Fragment loads (quarter-wave = 16
// consecutive rows) are contiguous 256 B -> fully coalesced.
#define OFF_SQ   ((size_t)Bn * Dn * 2)
#define OFF_POS  (OFF_SQ + Bn * 4)
#define OFF_NEG  (OFF_POS + Bn * 4)
#define OFF_ACC  (OFF_NEG + Bn * 4)   // [0]=total f32, [1]=count f32, [2]=ticket u32

// ---------------- prep: bf16 cast + k-group transpose, sq[i], init ----------
__global__ __launch_bounds__(256) void prep_kernel(
        const float* __restrict__ emb, unsigned short* __restrict__ embT,
        float* __restrict__ sq, unsigned int* __restrict__ posb,
        unsigned int* __restrict__ negb, unsigned int* __restrict__ accs) {
    const int w = threadIdx.x >> 6;
    const int lane = threadIdx.x & 63;
    const int row = blockIdx.x * 4 + w;   // grid = Bn/4, one wave per row

    const float4 v = *(const float4*)(emb + (size_t)row * Dn + lane * 4);
    float ss = v.x * v.x + v.y * v.y + v.z * v.z + v.w * v.w;
    #pragma unroll
    for (int m = 32; m >= 1; m >>= 1) ss += __shfl_xor(ss, m);

    uint2 o;
    o.x = (unsigned int)f2bf(v.x) | ((unsigned int)f2bf(v.y) << 16);
    o.y = (unsigned int)f2bf(v.z) | ((unsigned int)f2bf(v.w) << 16);
    // lane holds k = 4*lane .. 4*lane+3 -> k-group lane>>1, half lane&1
    const int kg = lane >> 1;
    *(uint2*)(embT + ((size_t)kg * Bn + row) * 8 + (lane & 1) * 4) = o;

    if (lane == 0) {
        sq[row] = ss;
        posb[row] = 0u;            // sentinel: real encoded scores are > 0
        negb[row] = 0xFFFFFFFFu;   // sentinel: real encoded scores are smaller
    }
    if (blockIdx.x == 0 && threadIdx.x == 0) {
        accs[0] = 0u; accs[1] = 0u; accs[2] = 0u;
    }
}

// ---------------- mine v5: counted-vmcnt 3-buffer pipeline (T3+T4+T5) -------
// R6 post-mortem: v2/v3/v4 (2x different LDS+VALU volumes) all ~46us, MfmaUtil
// pinned at 28% -> volume is NOT the constraint; the 2-phase STAGE->compute->
// __syncthreads() schedule is (syncthreads = s_waitcnt vmcnt(0) lgkmcnt(0) +
// s_barrier, draining the just-issued prefetch every jt; ~60% of cycles are
// stall). Escape per m218/m233: counted vmcnt across raw barriers. 3 LDS
// buffers, depth-2 prefetch: per jt issue STAGE(jt+2), compute buf[jt%3],
// then s_waitcnt vmcnt(4) (own STAGE(jt+1) landed; newest 4 loads stay in
// flight ACROSS the barrier) + s_barrier (all waves' STAGE(jt+1) landed).
// vmcnt never drains to 0 in steady state. setprio(1) wraps the MFMA cluster
// (T5: pays once the schedule has phase diversity).
__global__ __launch_bounds__(256, 2) void mine_kernel(
        const unsigned short* __restrict__ embT, const float* __restrict__ sq,
        const int* __restrict__ labels, unsigned int* __restrict__ posb,
        unsigned int* __restrict__ negb) {
    const int tid  = threadIdx.x;
    const int w    = tid >> 6;
    const int lane = tid & 63;
    const int quad = lane >> 4;
    const int c    = lane & 15;

    const int iBase = blockIdx.x * 256 + w * 64;   // block: 256 i, wave: 64 i
    const int jBase = blockIdx.y * 512;            // block j-window: 512

    const size_t KS = (size_t)4 * Bn * 8;   // shorts per k-step (4 k-groups)

    // LDS B tiles: 3 x 16 KB (unit (kg,j) at kg*32+j, 16 B each) + metadata.
    __shared__ __align__(16) unsigned short Bt[3][32 * 32 * 8];
    __shared__ float sqJ[512];
    __shared__ int   labJ[512];

    // A fragments: resident (AGPR-parked) for the whole j-loop. 4 m x 8 ks.
    short8 aFrag[4][8];
    #pragma unroll
    for (int m = 0; m < 4; ++m) {
        const unsigned short* ap = embT + ((size_t)quad * Bn + iBase + m * 16 + c) * 8;
        #pragma unroll
        for (int ks = 0; ks < 8; ++ks)
            aFrag[m][ks] = *(const short8*)(ap + ks * KS);
    }
    // Pin: an asm def can't be rematerialized -> fragments stay resident.
    #pragma unroll
    for (int m = 0; m < 4; ++m)
        #pragma unroll
        for (int ks = 0; ks < 8; ++ks)
            asm volatile("" : "+v"(aFrag[m][ks]));

    // labels of the rows this lane reduces (C/D rows: quad*4+r)
    int labI[4][4];
    #pragma unroll
    for (int m = 0; m < 4; ++m)
        #pragma unroll
        for (int r = 0; r < 4; ++r)
            labI[m][r] = labels[iBase + m * 16 + quad * 4 + r];

    float rpos[4][4], rneg[4][4];
    #pragma unroll
    for (int m = 0; m < 4; ++m)
        #pragma unroll
        for (int r = 0; r < 4; ++r) { rpos[m][r] = -1e30f; rneg[m][r] = 1e30f; }

    // Staging: thread t stages LDS units u = t + 256*cc (cc=0..3), which is
    // (kg = (t>>5) + 8*cc, jcol = t&31). LDS dest is wave-uniform base +
    // lane*16 (linear), global src is per-lane -> legal for global_load_lds.
    const unsigned short* sbase = embT + ((size_t)(tid >> 5) * Bn + jBase + (tid & 31)) * 8;

    #define STAGE(BUFP, JT) do {                                                       \
        const unsigned short* _s = sbase + (size_t)(JT) * 32 * 8;                      \
        unsigned short* _d = (BUFP) + (size_t)tid * 8;                                 \
        _Pragma("unroll")                                                              \
        for (int cc = 0; cc < 4; ++cc)                                                 \
            __builtin_amdgcn_global_load_lds(                                          \
                (const __attribute__((address_space(1))) unsigned int*)                \
                    (_s + (size_t)cc * 8 * Bn * 8),                                    \
                (__attribute__((address_space(3))) unsigned int*)(_d + cc * 256 * 8),  \
                16, 0, 0);                                                             \
    } while (0)

    // Prologue: two tiles in flight + metadata stage.
    STAGE(&Bt[0][0], 0);
    STAGE(&Bt[1][0], 1);
    {
        const int t2 = tid * 2;
        *(float2*)&sqJ[t2] = *(const float2*)&sq[jBase + t2];
        *(int2*)&labJ[t2]  = *(const int2*)&labels[jBase + t2];
    }
    // Own STAGE(0) landed (newest 4 = STAGE(1) stay in flight); ds_writes done.
    asm volatile("s_waitcnt vmcnt(4) lgkmcnt(0)" ::: "memory");
    __builtin_amdgcn_s_barrier();   // all waves' STAGE(0) landed

    int cur = 0;                    // buf index = jt % 3
    for (int jt = 0; jt < 16; ++jt) {
        const int s2 = (cur >= 1) ? cur - 1 : cur + 2;   // (jt+2) % 3
        if (jt + 2 < 16) STAGE(&Bt[s2][0], jt + 2);
        const unsigned short* bt = &Bt[cur][0];
        #pragma unroll
        for (int n = 0; n < 2; ++n) {
            const int jc = jt * 32 + n * 16 + c;
            const float sj = sqJ[jc];          // broadcast ds_read (quads share)
            const int   lj = labJ[jc];
            floatx4 acc[4];
            #pragma unroll
            for (int m = 0; m < 4; ++m) acc[m] = (floatx4){0.f, 0.f, 0.f, 0.f};
            __builtin_amdgcn_s_setprio(1);
            #pragma unroll
            for (int ks = 0; ks < 8; ++ks) {
                short8 bF = *(const short8*)(bt +
                    (size_t)((ks * 4 + quad) * 32 + n * 16 + c) * 8);
                #pragma unroll
                for (int m = 0; m < 4; ++m)
                    acc[m] = __builtin_amdgcn_mfma_f32_16x16x32_bf16(
                        aFrag[m][ks], bF, acc[m], 0, 0, 0);
            }
            __builtin_amdgcn_s_setprio(0);
            // s = sq_j - 2*dot: monotone proxy for dist. Diagonal is the
            // row-minimum s -> harmless inside the positive-max.
            #pragma unroll
            for (int m = 0; m < 4; ++m)
                #pragma unroll
                for (int r = 0; r < 4; ++r) {
                    float s = fmaf(-2.0f, acc[m][r], sj);
                    bool  e = (lj == labI[m][r]);
                    rpos[m][r] = e ? fmaxf(rpos[m][r], s) : rpos[m][r];
                    rneg[m][r] = e ? rneg[m][r] : fminf(rneg[m][r], s);
                }
        }
        // Wait for next tile (issued 1 iter ago) WITHOUT draining the one
        // issued this iter; barrier makes it block-wide. jt=14: nothing was
        // staged this iter -> drain. jt=15: loop ends, nothing to wait for.
        if (jt < 14) {
            asm volatile("s_waitcnt vmcnt(4)" ::: "memory");
            __builtin_amdgcn_s_barrier();
        } else if (jt == 14) {
            asm volatile("s_waitcnt vmcnt(0)" ::: "memory");
            __builtin_amdgcn_s_barrier();
        }
        cur = (cur == 2) ? 0 : cur + 1;
    }
    #undef STAGE

    // reduce over the 16 c-lanes of each quad; encode s+4 (>0) so uint order
    // == float order; merge via atomics.
    #pragma unroll
    for (int m = 0; m < 4; ++m)
        #pragma unroll
        for (int r = 0; r < 4; ++r) {
            float p = rpos[m][r], q = rneg[m][r];
            #pragma unroll
            for (int msk = 1; msk <= 8; msk <<= 1) {
                p = fmaxf(p, __shfl_xor(p, msk));
                q = fminf(q, __shfl_xor(q, msk));
            }
            if (c == 0) {
                int ig = iBase + m * 16 + quad * 4 + r;
                if (p > -1e29f) atomicMax(&posb[ig], __float_as_uint(p + 4.0f));
                if (q <  1e29f) atomicMin(&negb[ig], __float_as_uint(q + 4.0f));
            }
        }
}

// ---------------- finalize: partial sums + last-block divide -----------------
__global__ __launch_bounds__(256) void finalize_kernel(
        const float* __restrict__ sq, const unsigned int* __restrict__ posb,
        const unsigned int* __restrict__ negb, float* __restrict__ accsF,
        unsigned int* __restrict__ accsU, float* __restrict__ out) {
    const int i = blockIdx.x * 256 + threadIdx.x;
    unsigned int pb = posb[i], nb = negb[i];
    bool hp = (pb != 0u);
    bool hn = (nb != 0xFFFFFFFFu);
    float si  = sq[i];
    float dap = sqrtf(fmaxf(si + (__uint_as_float(pb) - 4.0f), 0.0f));
    float dan = sqrtf(fmaxf(si + (__uint_as_float(nb) - 4.0f), 0.0f));
    bool valid = hp && hn && (dan < dap + MARGIN_F);
    float t  = valid ? fmaxf(dap - dan + MARGIN_F, 0.0f) : 0.0f;
    float cc = valid ? 1.0f : 0.0f;
    #pragma unroll
    for (int m = 32; m >= 1; m >>= 1) {
        t  += __shfl_xor(t, m);
        cc += __shfl_xor(cc, m);
    }
    __shared__ float sT[4], sC[4];
    int w = threadIdx.x >> 6, lane = threadIdx.x & 63;
    if (lane == 0) { sT[w] = t; sC[w] = cc; }
    __syncthreads();
    if (threadIdx.x == 0) {
        atomicAdd(&accsF[0], sT[0] + sT[1] + sT[2] + sT[3]);
        atomicAdd(&accsF[1], sC[0] + sC[1] + sC[2] + sC[3]);
        __threadfence();
        unsigned int ticket = atomicAdd(&accsU[2], 1u);
        if (ticket == gridDim.x - 1) {
            float tot = atomicAdd(&accsF[0], 0.0f);
            float cnt = atomicAdd(&accsF[1], 0.0f);
            out[0] = (cnt > 0.0f) ? tot / cnt : 0.0f;
        }
    }
}

extern "C" void kernel_launch(void* const* d_in, const int* in_sizes, int n_in,
                              void* d_out, int out_size, void* d_ws, size_t ws_size,
                              hipStream_t stream) {
    const float* emb   = (const float*)d_in[0];
    const int*  labels = (const int*)d_in[1];
    float* out = (float*)d_out;

    char* ws = (char*)d_ws;
    unsigned short* embT = (unsigned short*)ws;
    float*        sqv  = (float*)(ws + OFF_SQ);
    unsigned int* posb = (unsigned int*)(ws + OFF_POS);
    unsigned int* negb = (unsigned int*)(ws + OFF_NEG);
    float*        accsF = (float*)(ws + OFF_ACC);
    unsigned int* accsU = (unsigned int*)(ws + OFF_ACC);

    prep_kernel<<<Bn / 4, 256, 0, stream>>>(emb, embT, sqv, posb, negb, accsU);
    mine_kernel<<<dim3(32, 16), 256, 0, stream>>>(embT, sqv, labels, posb, negb);
    finalize_kernel<<<Bn / 256, 256, 0, stream>>>(sqv, posb, negb, accsF, accsU, out);
}